// Round 1
// 282.941 us; speedup vs baseline: 1.0036x; 1.0036x over previous
//
#include <hip/hip_runtime.h>

// QAttentionLayer: out[..., i] = prod_{j<=i} cos(x_j)*cos(w_j), rows of 10 fp32.
// Memory-bound streaming (335 MB traffic -> ~53 us kernel floor).
//
// R2 changes vs R1 (283.97 us bench = ~201 us harness fills + ~83 us kernel @ 4.0 TB/s):
//  1. Row-PAIR processing: 2 rows = 80 B = 5x float4, 16B-aligned in LDS.
//     LDS access becomes 5 ds_read_b128 + 5 ds_write_b128 per thread at the
//     128 B/clk data-rate floor (8 lanes/bank-quad), replacing 40 scalar ops
//     with 4-way bank conflicts (stride-10 words, gcd(10,32)=2 -> 4 lanes/bank).
//  2. global_load_lds width=16 staging: DMA straight into LDS, no VGPR
//     round-trip, no staging ds_writes (guide m97: compiler never auto-emits).
// Predicted: kernel ~83 -> ~60-65 us; bench ~284 -> ~260-266 us.

#define BLOCK 256
#define ROWS_PER_BLOCK 512                       // 2 rows per thread (1 pair)
#define NQ 10
#define WORDS_PER_BLOCK (ROWS_PER_BLOCK * NQ)    // 5120 fp32 = 20480 B -> 8 blocks/CU
#define U4_PER_BLOCK (WORDS_PER_BLOCK / 4)       // 1280 float4
#define U4_PER_THREAD (U4_PER_BLOCK / BLOCK)     // 5

__global__ __launch_bounds__(BLOCK) void qcircuit_kernel(
    const float* __restrict__ x,
    const float* __restrict__ w,
    float* __restrict__ out,
    int n_rows)
{
    __shared__ float4 buf4[U4_PER_BLOCK];
    float* bufw = (float*)buf4;

    const int tid = threadIdx.x;
    const long long block_row0 = (long long)blockIdx.x * ROWS_PER_BLOCK;
    const long long total_u4   = ((long long)n_rows * NQ) / 4;
    const long long u4_base    = (long long)blockIdx.x * U4_PER_BLOCK;
    const float4* __restrict__ gin  = (const float4*)x;
    float4* __restrict__       gout = (float4*)out;

    // ---- async global -> LDS stage (16 B/lane DMA, linear layout) ----
    #pragma unroll
    for (int k = 0; k < U4_PER_THREAD; ++k) {
        long long gi = u4_base + (long long)(k * BLOCK + tid);
        if (gi < total_u4) {
            __builtin_amdgcn_global_load_lds(
                (const __attribute__((address_space(1))) void*)(gin + gi),
                (__attribute__((address_space(3))) void*)(buf4 + k * BLOCK + tid),
                16, 0, 0);
        }
    }

    // cos(weights): uniform scalar loads, overlapped with the in-flight DMA
    float cw[NQ];
    #pragma unroll
    for (int j = 0; j < NQ; ++j) cw[j] = __cosf(w[j]);

    __syncthreads();   // compiler drains vmcnt(0) before s_barrier -> DMA complete

    // ---- process one ROW-PAIR per thread: 5x b128 read, compute, 5x b128 write ----
    const long long row0 = block_row0 + 2LL * tid;
    if (row0 + 1 < n_rows) {
        float v[20];                       // fully static indexing -> stays in VGPRs
        float4* vr = (float4*)v;
        #pragma unroll
        for (int k = 0; k < 5; ++k) vr[k] = buf4[tid * 5 + k];

        float p = 1.0f;
        #pragma unroll
        for (int j = 0; j < NQ; ++j) { p *= __cosf(v[j]) * cw[j]; v[j] = p; }
        p = 1.0f;
        #pragma unroll
        for (int j = 0; j < NQ; ++j) { p *= __cosf(v[NQ + j]) * cw[j]; v[NQ + j] = p; }

        #pragma unroll
        for (int k = 0; k < 5; ++k) buf4[tid * 5 + k] = vr[k];
    } else if (row0 < n_rows) {
        // odd tail row (never hit at bench shape): scalar in-place
        float p = 1.0f;
        #pragma unroll
        for (int j = 0; j < NQ; ++j) {
            float t = bufw[2 * tid * NQ + j];
            p *= __cosf(t) * cw[j];
            bufw[2 * tid * NQ + j] = p;
        }
    }

    __syncthreads();

    // ---- coalesced LDS -> global store (16 B/lane) ----
    #pragma unroll
    for (int k = 0; k < U4_PER_THREAD; ++k) {
        long long gi = u4_base + (long long)(k * BLOCK + tid);
        if (gi < total_u4) gout[gi] = buf4[k * BLOCK + tid];
    }
}

extern "C" void kernel_launch(void* const* d_in, const int* in_sizes, int n_in,
                              void* d_out, int out_size, void* d_ws, size_t ws_size,
                              hipStream_t stream) {
    const float* x = (const float*)d_in[0];
    const float* w = (const float*)d_in[1];
    float* out = (float*)d_out;

    const int n_elem = in_sizes[0];
    const int n_rows = n_elem / NQ;
    const int blocks = (n_rows + ROWS_PER_BLOCK - 1) / ROWS_PER_BLOCK;

    hipLaunchKernelGGL(qcircuit_kernel, dim3(blocks), dim3(BLOCK), 0, stream,
                       x, w, out, n_rows);
}